// Round 1
// baseline (2510.149 us; speedup 1.0000x reference)
//
#include <hip/hip_runtime.h>
#include <cmath>

typedef unsigned short u16;
typedef unsigned int u32;
typedef __bf16 bf16x8 __attribute__((ext_vector_type(8)));
typedef float f32x4 __attribute__((ext_vector_type(4)));

__device__ __forceinline__ u16 f2bf(float f) {
  u32 u = __float_as_uint(f);
  u32 r = (u + 0x7FFFu + ((u >> 16) & 1u)) >> 16;
  return (u16)r;
}
__device__ __forceinline__ float bf2f(u32 h) { return __uint_as_float(h << 16); }
__device__ __forceinline__ float swishf(float y) { return y / (1.0f + __expf(-y)); }

// ---------------- coord stats: per-batch mean + scale ----------------
__global__ void k_coordstats(const float* __restrict__ coords, float* __restrict__ cstat) {
  const int b = blockIdx.x, t = threadIdx.x;
  __shared__ float red[256];
  __shared__ float msh[4];
  float s0 = 0.f, s1 = 0.f, s2 = 0.f;
  for (int n = t; n < 32768; n += 256) {
    s0 += coords[(b * 3 + 0) * 32768 + n];
    s1 += coords[(b * 3 + 1) * 32768 + n];
    s2 += coords[(b * 3 + 2) * 32768 + n];
  }
  float sv[3] = {s0, s1, s2};
  for (int a = 0; a < 3; ++a) {
    red[t] = sv[a];
    __syncthreads();
    for (int w = 128; w > 0; w >>= 1) {
      if (t < w) red[t] += red[t + w];
      __syncthreads();
    }
    if (t == 0) msh[a] = red[0] * (1.0f / 32768.0f);
    __syncthreads();
  }
  const float mx = msh[0], my = msh[1], mz = msh[2];
  float mv = 0.f;
  for (int n = t; n < 32768; n += 256) {
    float dx = coords[(b * 3 + 0) * 32768 + n] - mx;
    float dy = coords[(b * 3 + 1) * 32768 + n] - my;
    float dz = coords[(b * 3 + 2) * 32768 + n] - mz;
    mv = fmaxf(mv, sqrtf(dx * dx + dy * dy + dz * dz));
  }
  red[t] = mv;
  __syncthreads();
  for (int w = 128; w > 0; w >>= 1) {
    if (t < w) red[t] = fmaxf(red[t], red[t + w]);
    __syncthreads();
  }
  if (t == 0) {
    float4 r;
    r.x = mx; r.y = my; r.z = mz; r.w = red[0] * 2.0f;
    ((float4*)cstat)[b] = r;
  }
}

// ---------------- voxelize: norm coords + scatter-add ----------------
__global__ void k_voxelize(const float* __restrict__ coords, const float* __restrict__ feat,
                           const float* __restrict__ cstat, float4* __restrict__ nrm,
                           float* __restrict__ cnt, float* __restrict__ gs) {
  const int idx = blockIdx.x * 256 + threadIdx.x;  // 262144
  const int b = idx >> 15, n = idx & 32767;
  const float4 cs = ((const float4*)cstat)[b];
  const float inv = 1.0f / cs.w;
  float nx = ((coords[(b * 3 + 0) * 32768 + n] - cs.x) * inv + 0.5f) * 32.0f;
  float ny = ((coords[(b * 3 + 1) * 32768 + n] - cs.y) * inv + 0.5f) * 32.0f;
  float nz = ((coords[(b * 3 + 2) * 32768 + n] - cs.z) * inv + 0.5f) * 32.0f;
  nx = fminf(fmaxf(nx, 0.0f), 31.0f);
  ny = fminf(fmaxf(ny, 0.0f), 31.0f);
  nz = fminf(fmaxf(nz, 0.0f), 31.0f);
  float4 o; o.x = nx; o.y = ny; o.z = nz; o.w = 0.f;
  nrm[idx] = o;
  const int ix = (int)rintf(nx), iy = (int)rintf(ny), iz = (int)rintf(nz);
  const int v = (ix << 10) + (iy << 5) + iz;
  atomicAdd(&cnt[(b << 15) + v], 1.0f);
  const float* fb = feat + ((size_t)b << 21) + n;   // b*64*32768
  float* gp = gs + ((size_t)((b << 15) + v) << 6);  // [b][v][64]
#pragma unroll 4
  for (int c = 0; c < 64; ++c) atomicAdd(gp + c, fb[(size_t)c << 15]);
}

// ---------------- finalize grid: mean + bf16 ----------------
__global__ void k_finalize(const float* __restrict__ gs, const float* __restrict__ cnt,
                           u16* __restrict__ gb) {
  const int idx = blockIdx.x * 256 + threadIdx.x;  // 2097152
  const int e0 = idx << 3;
  const int bv = e0 >> 6;
  const float inv = 1.0f / fmaxf(cnt[bv], 1.0f);
  const float4 sa = ((const float4*)gs)[idx * 2];
  const float4 sb = ((const float4*)gs)[idx * 2 + 1];
  uint4 o;
  o.x = (u32)f2bf(sa.x * inv) | ((u32)f2bf(sa.y * inv) << 16);
  o.y = (u32)f2bf(sa.z * inv) | ((u32)f2bf(sa.w * inv) << 16);
  o.z = (u32)f2bf(sb.x * inv) | ((u32)f2bf(sb.y * inv) << 16);
  o.w = (u32)f2bf(sb.z * inv) | ((u32)f2bf(sb.w * inv) << 16);
  ((uint4*)gb)[idx] = o;
}

// ---------------- weight repack: [co][ci][27] f32 -> [off][co][ci] bf16 ----------------
template <int CI>
__global__ void k_prepw(const float* __restrict__ w, u16* __restrict__ wr) {
  const int idx = blockIdx.x * 256 + threadIdx.x;
  if (idx >= 27 * 128 * CI) return;
  const int off = idx / (128 * CI);
  const int rem = idx - off * (128 * CI);
  const int co = rem / CI;
  const int ci = rem - co * CI;
  wr[idx] = f2bf(w[(co * CI + ci) * 27 + off]);
}

// ---------------- conv3d 3x3x3 SAME, implicit GEMM via MFMA bf16 ----------------
// in:[8][32768(v=x*1024+y*32+z)][CI] bf16, W:[27][128][CI] bf16, out:[8][32768][128] bf16
// block: (x-quad, y, b); M=128 co x N=128 (4 z-pencils). 4 waves, each 4mx4n 16x16 tiles.
template <int CI>
__launch_bounds__(256, 2)
__global__ void k_conv(const u16* __restrict__ in, const u16* __restrict__ W,
                       const float* __restrict__ bias, u16* __restrict__ outp,
                       float* __restrict__ ssum, float* __restrict__ ssq) {
  constexpr int CIC = 40;  // padded ci stride (keeps ds_read_b128 aligned, spreads banks)
  __shared__ u16 lin[612 * CIC];  // [xs6][ys3][z34][40] = 48960 B
  const int t = threadIdx.x;
  const int wave = t >> 6, lane = t & 63;
  const int l15 = lane & 15, quad = lane >> 4;
  const int x0 = blockIdx.x << 2;
  const int y = blockIdx.y;
  const int b = blockIdx.z;
  const int mq = wave & 1, nq = wave >> 1;

  f32x4 acc[4][4];
#pragma unroll
  for (int i = 0; i < 4; ++i)
#pragma unroll
    for (int j = 0; j < 4; ++j) acc[i][j] = (f32x4)0.0f;

  for (int cc = 0; cc < CI / 32; ++cc) {
    __syncthreads();
    const int ci0 = cc << 5;
    for (int id = t; id < 2448; id += 256) {  // 612 rows x 4 x 16B
      const int row = id >> 2, c16 = id & 3;
      const int xs = row / 102, rem = row - xs * 102;
      const int ys = rem / 34, zp = rem - ys * 34;
      const int x = x0 + xs - 1, yy = y + ys - 1, zz = zp - 1;
      uint4 val = make_uint4(0u, 0u, 0u, 0u);
      if ((u32)x < 32u && (u32)yy < 32u && (u32)zz < 32u)
        val = *(const uint4*)(in + (((b << 15) + (x << 10) + (yy << 5) + zz) * CI + ci0 + (c16 << 3)));
      *(uint4*)(lin + row * CIC + (c16 << 3)) = val;
    }
    __syncthreads();

#pragma unroll 1
    for (int off = 0; off < 27; ++off) {
      const int dx = off / 9, r9 = off - dx * 9;
      const int dy = r9 / 3, dz = r9 - dy * 3;
      bf16x8 af[4];
#pragma unroll
      for (int mt = 0; mt < 4; ++mt) {
        const int co = (mq << 6) + (mt << 4) + l15;
        af[mt] = *(const bf16x8*)(W + ((off << 7) + co) * CI + ci0 + (quad << 3));
      }
      bf16x8 bfr[4];
#pragma unroll
      for (int nt = 0; nt < 4; ++nt) {
        const int px = (nq << 1) + (nt >> 1);
        const int z = ((nt & 1) << 4) + l15;
        const int rowi = ((px + dx) * 3 + dy) * 34 + z + dz;
        bfr[nt] = *(const bf16x8*)(lin + rowi * CIC + (quad << 3));
      }
#pragma unroll
      for (int mt = 0; mt < 4; ++mt)
#pragma unroll
        for (int nt = 0; nt < 4; ++nt)
          acc[mt][nt] = __builtin_amdgcn_mfma_f32_16x16x32_bf16(af[mt], bfr[nt], acc[mt][nt], 0, 0, 0);
    }
  }

  // epilogue: +bias, bf16 store, per-channel sum/sumsq (for GN)
  float ps[16], pq[16];
#pragma unroll
  for (int i = 0; i < 16; ++i) { ps[i] = 0.f; pq[i] = 0.f; }
#pragma unroll
  for (int mt = 0; mt < 4; ++mt) {
    const int co0 = (mq << 6) + (mt << 4) + (quad << 2);
    const float4 b4 = *(const float4*)(bias + co0);
#pragma unroll
    for (int nt = 0; nt < 4; ++nt) {
      const int px = (nq << 1) + (nt >> 1);
      const int z = ((nt & 1) << 4) + l15;
      const int v = ((x0 + px) << 10) + (y << 5) + z;
      const float v0 = acc[mt][nt][0] + b4.x;
      const float v1 = acc[mt][nt][1] + b4.y;
      const float v2 = acc[mt][nt][2] + b4.z;
      const float v3 = acc[mt][nt][3] + b4.w;
      ps[mt * 4 + 0] += v0; pq[mt * 4 + 0] += v0 * v0;
      ps[mt * 4 + 1] += v1; pq[mt * 4 + 1] += v1 * v1;
      ps[mt * 4 + 2] += v2; pq[mt * 4 + 2] += v2 * v2;
      ps[mt * 4 + 3] += v3; pq[mt * 4 + 3] += v3 * v3;
      uint2 pk;
      pk.x = (u32)f2bf(v0) | ((u32)f2bf(v1) << 16);
      pk.y = (u32)f2bf(v2) | ((u32)f2bf(v3) << 16);
      *(uint2*)(outp + ((b << 15) + v) * 128 + co0) = pk;
    }
  }
#pragma unroll
  for (int i = 0; i < 16; ++i) {
#pragma unroll
    for (int d = 1; d < 16; d <<= 1) {
      ps[i] += __shfl_xor(ps[i], d);
      pq[i] += __shfl_xor(pq[i], d);
    }
  }
  if (l15 == 0) {
#pragma unroll
    for (int mt = 0; mt < 4; ++mt)
#pragma unroll
      for (int r = 0; r < 4; ++r) {
        const int co = (mq << 6) + (mt << 4) + (quad << 2) + r;
        atomicAdd(&ssum[b * 128 + co], ps[mt * 4 + r]);
        atomicAdd(&ssq[b * 128 + co], pq[mt * 4 + r]);
      }
  }
}

// ---------------- GN -> per-(b,c) affine ----------------
__global__ void k_gnaff(const float* __restrict__ s, const float* __restrict__ q,
                        const float* __restrict__ gg, const float* __restrict__ gb,
                        float* __restrict__ A, float* __restrict__ B) {
  const int b = blockIdx.x, c = threadIdx.x;  // 128 threads
  __shared__ float gs[8], gq[8];
  if (c < 8) { gs[c] = 0.f; gq[c] = 0.f; }
  __syncthreads();
  const float sc = s[b * 128 + c], qc = q[b * 128 + c];
  atomicAdd(&gs[c >> 4], sc);
  atomicAdd(&gq[c >> 4], qc);
  __syncthreads();
  const float inv = 1.0f / 524288.0f;  // 16 ch * 32768
  const float mg = gs[c >> 4] * inv;
  const float var = gq[c >> 4] * inv - mg * mg;
  const float rs = rsqrtf(var + 1e-5f);
  const float a = gg[c] * rs;
  A[b * 128 + c] = a;
  B[b * 128 + c] = gb[c] - mg * a;
}

// ---------------- GN2 + SE -> per-(b,c) affine ----------------
__global__ void k_se(const float* __restrict__ s, const float* __restrict__ q,
                     const float* __restrict__ gg, const float* __restrict__ gb,
                     const float* __restrict__ w1, const float* __restrict__ b1,
                     const float* __restrict__ w2, const float* __restrict__ b2,
                     float* __restrict__ A, float* __restrict__ B) {
  const int b = blockIdx.x, c = threadIdx.x;  // 128 threads
  __shared__ float gs[8], gq[8], sarr[128], h[16];
  if (c < 8) { gs[c] = 0.f; gq[c] = 0.f; }
  __syncthreads();
  const float sc = s[b * 128 + c], qc = q[b * 128 + c];
  atomicAdd(&gs[c >> 4], sc);
  atomicAdd(&gq[c >> 4], qc);
  __syncthreads();
  const float inv = 1.0f / 524288.0f;
  const float mg = gs[c >> 4] * inv;
  const float var = gq[c >> 4] * inv - mg * mg;
  const float rs = rsqrtf(var + 1e-5f);
  const float a = gg[c] * rs;
  const float bb = gb[c] - mg * a;
  sarr[c] = (sc * (1.0f / 32768.0f)) * a + bb;  // spatial mean of GN output
  __syncthreads();
  if (c < 16) {
    float accv = b1[c];
    for (int i = 0; i < 128; ++i) accv += w1[c * 128 + i] * sarr[i];
    h[c] = fmaxf(accv, 0.f);
  }
  __syncthreads();
  float o = b2[c];
  for (int r = 0; r < 16; ++r) o += w2[c * 16 + r] * h[r];
  const float se = 1.0f / (1.0f + __expf(-o));
  A[b * 128 + c] = a * se;
  B[b * 128 + c] = bb * se;
}

// ---------------- GN1 apply + swish, bf16->bf16 ----------------
__global__ void k_gnapply(const u16* __restrict__ x, const float* __restrict__ A,
                          const float* __restrict__ B, u16* __restrict__ outp) {
  const int idx = blockIdx.x * 256 + threadIdx.x;  // 4194304
  const int e0 = idx << 3;
  const int b = e0 >> 22;
  const int c0 = e0 & 127;
  const uint4 v = ((const uint4*)x)[idx];
  const float* Ab = A + b * 128 + c0;
  const float* Bb = B + b * 128 + c0;
  u32 vv[4] = {v.x, v.y, v.z, v.w};
  uint4 o;
  u32 rr[4];
#pragma unroll
  for (int i = 0; i < 4; ++i) {
    float y0 = bf2f(vv[i] & 0xffffu) * Ab[2 * i] + Bb[2 * i];
    float y1 = bf2f(vv[i] >> 16) * Ab[2 * i + 1] + Bb[2 * i + 1];
    y0 = swishf(y0);
    y1 = swishf(y1);
    rr[i] = (u32)f2bf(y0) | ((u32)f2bf(y1) << 16);
  }
  o.x = rr[0]; o.y = rr[1]; o.z = rr[2]; o.w = rr[3];
  ((uint4*)outp)[idx] = o;
}

// ---------------- point branch GEMM: pt = pt_w @ features + b -> d_out (raw f32) ----------------
__launch_bounds__(256, 2)
__global__ void k_pt(const float* __restrict__ feat, const float* __restrict__ pw,
                     const float* __restrict__ pb, float* __restrict__ outp,
                     float* __restrict__ ssum, float* __restrict__ ssq) {
  __shared__ float fl[64 * 64];    // [k][n]
  __shared__ float wl[64 * 132];   // [k][c] padded
  const int t = threadIdx.x;
  const int n0g = blockIdx.x << 6;
  const int b = blockIdx.y;
  for (int i = t; i < 1024; i += 256) {
    const int fi = i << 2;
    const int k = fi >> 6, n = fi & 63;
    *(float4*)(fl + fi) = *(const float4*)(feat + ((size_t)(b * 64 + k) << 15) + n0g + n);
  }
  for (int i = t; i < 8192; i += 256) {
    const int c = i >> 6, k = i & 63;
    wl[k * 132 + c] = pw[i];
  }
  __syncthreads();
  const int tc = t >> 3, tn = t & 7;
  const int c0 = tc << 2, n0 = tn << 3;
  float acc[4][8];
#pragma unroll
  for (int i = 0; i < 4; ++i)
#pragma unroll
    for (int j = 0; j < 8; ++j) acc[i][j] = 0.f;
#pragma unroll 4
  for (int k = 0; k < 64; ++k) {
    const float4 a4 = *(const float4*)(wl + k * 132 + c0);
    const float4 b0 = *(const float4*)(fl + (k << 6) + n0);
    const float4 b1 = *(const float4*)(fl + (k << 6) + n0 + 4);
    const float av[4] = {a4.x, a4.y, a4.z, a4.w};
    const float bv[8] = {b0.x, b0.y, b0.z, b0.w, b1.x, b1.y, b1.z, b1.w};
#pragma unroll
    for (int i = 0; i < 4; ++i)
#pragma unroll
      for (int j = 0; j < 8; ++j) acc[i][j] += av[i] * bv[j];
  }
#pragma unroll
  for (int i = 0; i < 4; ++i) {
    const int c = c0 + i;
    const float bias = pb[c];
    float s = 0.f, q = 0.f;
    float vv[8];
#pragma unroll
    for (int j = 0; j < 8; ++j) {
      vv[j] = acc[i][j] + bias;
      s += vv[j];
      q += vv[j] * vv[j];
    }
    float4 o0, o1;
    o0.x = vv[0]; o0.y = vv[1]; o0.z = vv[2]; o0.w = vv[3];
    o1.x = vv[4]; o1.y = vv[5]; o1.z = vv[6]; o1.w = vv[7];
    float* op = outp + (((size_t)(b * 128 + c)) << 15) + n0g + n0;
    *(float4*)op = o0;
    *(float4*)(op + 4) = o1;
    for (int d = 1; d < 8; d <<= 1) {
      s += __shfl_xor(s, d);
      q += __shfl_xor(q, d);
    }
    if (tn == 0) {
      atomicAdd(&ssum[b * 128 + c], s);
      atomicAdd(&ssq[b * 128 + c], q);
    }
  }
}

// ---------------- trilinear devox (w/ GN2*SE affine) + point branch (GN3 affine + swish) ----------------
__launch_bounds__(256)
__global__ void k_devox(const u16* __restrict__ g, const float4* __restrict__ nrm,
                        const float* __restrict__ A2, const float* __restrict__ B2,
                        const float* __restrict__ A3, const float* __restrict__ B3,
                        float* __restrict__ outp) {
  __shared__ float tri[64][129];
  const int t = threadIdx.x;
  const int blk = blockIdx.x, b = blockIdx.y;
  {
    const int pl = t & 63, cg = t >> 6;
    const float4 nc = nrm[(b << 15) + blk * 64 + pl];
    const int ix0 = (int)floorf(nc.x), iy0 = (int)floorf(nc.y), iz0 = (int)floorf(nc.z);
    const float rx = nc.x - (float)ix0, ry = nc.y - (float)iy0, rz = nc.z - (float)iz0;
    const int ix1 = min(ix0 + 1, 31), iy1 = min(iy0 + 1, 31), iz1 = min(iz0 + 1, 31);
    float acc[32];
#pragma unroll
    for (int i = 0; i < 32; ++i) acc[i] = 0.f;
    for (int cr = 0; cr < 8; ++cr) {
      const int xx = (cr & 4) ? ix1 : ix0;
      const int yv = (cr & 2) ? iy1 : iy0;
      const int zv = (cr & 1) ? iz1 : iz0;
      const float w = ((cr & 4) ? rx : 1.f - rx) * ((cr & 2) ? ry : 1.f - ry) *
                      ((cr & 1) ? rz : 1.f - rz);
      const uint4* src =
          (const uint4*)(g + ((size_t)((b << 15) + (xx << 10) + (yv << 5) + zv) << 7) + (cg << 5));
#pragma unroll
      for (int qq = 0; qq < 4; ++qq) {
        const uint4 u = src[qq];
        acc[qq * 8 + 0] += w * bf2f(u.x & 0xffffu);
        acc[qq * 8 + 1] += w * bf2f(u.x >> 16);
        acc[qq * 8 + 2] += w * bf2f(u.y & 0xffffu);
        acc[qq * 8 + 3] += w * bf2f(u.y >> 16);
        acc[qq * 8 + 4] += w * bf2f(u.z & 0xffffu);
        acc[qq * 8 + 5] += w * bf2f(u.z >> 16);
        acc[qq * 8 + 6] += w * bf2f(u.w & 0xffffu);
        acc[qq * 8 + 7] += w * bf2f(u.w >> 16);
      }
    }
    const int cb = b * 128 + (cg << 5);
#pragma unroll
    for (int i = 0; i < 32; ++i) tri[pl][(cg << 5) + i] = acc[i] * A2[cb + i] + B2[cb + i];
  }
  __syncthreads();
  {
    const int nl = t & 63, cg = t >> 6;
#pragma unroll 4
    for (int i = 0; i < 32; ++i) {
      const int c = (cg << 5) + i;
      const size_t oi = (((size_t)(b * 128 + c)) << 15) + blk * 64 + nl;
      const float pv = outp[oi];
      const float y = pv * A3[b * 128 + c] + B3[b * 128 + c];
      outp[oi] = tri[nl][c] + swishf(y);
    }
  }
}

extern "C" void kernel_launch(void* const* d_in, const int* in_sizes, int n_in,
                              void* d_out, int out_size, void* d_ws, size_t ws_size,
                              hipStream_t stream) {
  const float* features = (const float*)d_in[0];
  const float* coords = (const float*)d_in[1];
  const float* conv1_w = (const float*)d_in[2];
  const float* conv1_b = (const float*)d_in[3];
  const float* gn1_g = (const float*)d_in[4];
  const float* gn1_b = (const float*)d_in[5];
  const float* conv2_w = (const float*)d_in[6];
  const float* conv2_b = (const float*)d_in[7];
  const float* gn2_g = (const float*)d_in[8];
  const float* gn2_b = (const float*)d_in[9];
  const float* se_w1 = (const float*)d_in[10];
  const float* se_b1 = (const float*)d_in[11];
  const float* se_w2 = (const float*)d_in[12];
  const float* se_b2 = (const float*)d_in[13];
  const float* pt_w = (const float*)d_in[14];
  const float* pt_b = (const float*)d_in[15];
  const float* ptgn_g = (const float*)d_in[16];
  const float* ptgn_b = (const float*)d_in[17];

  char* ws = (char*)d_ws;
  // stats block (zeroed): cstat[32] | s1,q1 | s2,q2 | s3,q3 | A1,B1 | A2,B2 | A3,B3
  float* cstat = (float*)ws;
  float* s1 = cstat + 32;
  float* q1 = s1 + 1024;
  float* s2 = q1 + 1024;
  float* q2 = s2 + 1024;
  float* s3 = q2 + 1024;
  float* q3 = s3 + 1024;
  float* A1 = q3 + 1024;
  float* B1 = A1 + 1024;
  float* A2 = B1 + 1024;
  float* B2 = A2 + 1024;
  float* A3 = B2 + 1024;
  float* B3 = A3 + 1024;
  size_t o = 65536;
  u16* Wr1 = (u16*)(ws + o); o += (size_t)27 * 128 * 64 * 2;
  u16* Wr2 = (u16*)(ws + o); o += (size_t)27 * 128 * 128 * 2;
  o = (o + 255) & ~(size_t)255;
  float4* nrm = (float4*)(ws + o); o += (size_t)8 * 32768 * 16;
  float* cnt = (float*)(ws + o); o += (size_t)8 * 32768 * 4;
  char* regA = ws + o; o += (size_t)8 * 32768 * 128 * 2;  // gridsum f32 / conv1raw / conv2raw
  u16* gridbf = (u16*)(ws + o); o += (size_t)8 * 32768 * 64 * 2;
  u16* c2in = (u16*)(ws + o); o += (size_t)8 * 32768 * 128 * 2;
  float* gsum = (float*)regA;
  u16* c1raw = (u16*)regA;
  u16* c2raw = (u16*)regA;

  hipMemsetAsync(cstat, 0, 65536, stream);
  hipMemsetAsync(cnt, 0, (size_t)8 * 32768 * 4, stream);
  hipMemsetAsync(gsum, 0, (size_t)8 * 32768 * 64 * 4, stream);

  k_prepw<64><<<dim3((27 * 128 * 64 + 255) / 256), 256, 0, stream>>>(conv1_w, Wr1);
  k_prepw<128><<<dim3((27 * 128 * 128 + 255) / 256), 256, 0, stream>>>(conv2_w, Wr2);
  k_coordstats<<<8, 256, 0, stream>>>(coords, cstat);
  k_voxelize<<<1024, 256, 0, stream>>>(coords, features, cstat, nrm, cnt, gsum);
  k_finalize<<<8192, 256, 0, stream>>>(gsum, cnt, gridbf);
  k_conv<64><<<dim3(8, 32, 8), 256, 0, stream>>>(gridbf, Wr1, conv1_b, c1raw, s1, q1);
  k_gnaff<<<8, 128, 0, stream>>>(s1, q1, gn1_g, gn1_b, A1, B1);
  k_gnapply<<<16384, 256, 0, stream>>>(c1raw, A1, B1, c2in);
  k_conv<128><<<dim3(8, 32, 8), 256, 0, stream>>>(c2in, Wr2, conv2_b, c2raw, s2, q2);
  k_pt<<<dim3(512, 8), 256, 0, stream>>>(features, pt_w, pt_b, (float*)d_out, s3, q3);
  k_se<<<8, 128, 0, stream>>>(s2, q2, gn2_g, gn2_b, se_w1, se_b1, se_w2, se_b2, A2, B2);
  k_gnaff<<<8, 128, 0, stream>>>(s3, q3, ptgn_g, ptgn_b, A3, B3);
  k_devox<<<dim3(512, 8), 256, 0, stream>>>(c2raw, nrm, A2, B2, A3, B3, (float*)d_out);
}

// Round 2
// 1749.112 us; speedup vs baseline: 1.4351x; 1.4351x over previous
//
#include <hip/hip_runtime.h>
#include <cmath>

typedef unsigned short u16;
typedef unsigned int u32;
typedef __bf16 bf16x8 __attribute__((ext_vector_type(8)));
typedef float f32x4 __attribute__((ext_vector_type(4)));

__device__ __forceinline__ u16 f2bf(float f) {
  u32 u = __float_as_uint(f);
  u32 r = (u + 0x7FFFu + ((u >> 16) & 1u)) >> 16;
  return (u16)r;
}
__device__ __forceinline__ float bf2f(u32 h) { return __uint_as_float(h << 16); }
__device__ __forceinline__ float swishf(float y) { return y / (1.0f + __expf(-y)); }

// ---------------- coord sums: atomic per-block partial sums ----------------
// cstat layout per b: [sx, sy, sz, maxnorm_bits]
__global__ void k_csum(const float* __restrict__ coords, float* __restrict__ cstat) {
  const int b = blockIdx.y, t = threadIdx.x;
  const int n0 = blockIdx.x * 1024;
  float s[3] = {0.f, 0.f, 0.f};
#pragma unroll
  for (int a = 0; a < 3; ++a) {
    const float* p = coords + (b * 3 + a) * 32768 + n0;
#pragma unroll
    for (int i = 0; i < 4; ++i) s[a] += p[t + i * 256];
  }
#pragma unroll
  for (int a = 0; a < 3; ++a) {
#pragma unroll
    for (int d = 1; d < 64; d <<= 1) s[a] += __shfl_xor(s[a], d);
    if ((t & 63) == 0) atomicAdd(&cstat[b * 4 + a], s[a]);
  }
}

__global__ void k_cmax(const float* __restrict__ coords, float* __restrict__ cstat) {
  const int b = blockIdx.y, t = threadIdx.x;
  const int n0 = blockIdx.x * 1024;
  const float mx = cstat[b * 4 + 0] * (1.0f / 32768.0f);
  const float my = cstat[b * 4 + 1] * (1.0f / 32768.0f);
  const float mz = cstat[b * 4 + 2] * (1.0f / 32768.0f);
  float mv = 0.f;
#pragma unroll
  for (int i = 0; i < 4; ++i) {
    const int n = n0 + t + i * 256;
    const float dx = coords[(b * 3 + 0) * 32768 + n] - mx;
    const float dy = coords[(b * 3 + 1) * 32768 + n] - my;
    const float dz = coords[(b * 3 + 2) * 32768 + n] - mz;
    mv = fmaxf(mv, dx * dx + dy * dy + dz * dz);
  }
#pragma unroll
  for (int d = 1; d < 64; d <<= 1) mv = fmaxf(mv, __shfl_xor(mv, d));
  if ((t & 63) == 0) atomicMax((u32*)&cstat[b * 4 + 3], __float_as_uint(sqrtf(mv)));
}

// ---------------- normalize coords, voxel id, histogram ----------------
__global__ void k_count(const float* __restrict__ coords, const float* __restrict__ cstat,
                        float4* __restrict__ nrm, int* __restrict__ vid, int* __restrict__ hist) {
  const int idx = blockIdx.x * 256 + threadIdx.x;  // 262144
  const int b = idx >> 15, n = idx & 32767;
  const float mx = cstat[b * 4 + 0] * (1.0f / 32768.0f);
  const float my = cstat[b * 4 + 1] * (1.0f / 32768.0f);
  const float mz = cstat[b * 4 + 2] * (1.0f / 32768.0f);
  const float mn = __uint_as_float(__float_as_uint(cstat[b * 4 + 3]));
  const float inv = 1.0f / (mn * 2.0f);
  float nx = ((coords[(b * 3 + 0) * 32768 + n] - mx) * inv + 0.5f) * 32.0f;
  float ny = ((coords[(b * 3 + 1) * 32768 + n] - my) * inv + 0.5f) * 32.0f;
  float nz = ((coords[(b * 3 + 2) * 32768 + n] - mz) * inv + 0.5f) * 32.0f;
  nx = fminf(fmaxf(nx, 0.0f), 31.0f);
  ny = fminf(fmaxf(ny, 0.0f), 31.0f);
  nz = fminf(fmaxf(nz, 0.0f), 31.0f);
  float4 o; o.x = nx; o.y = ny; o.z = nz; o.w = 0.f;
  nrm[idx] = o;
  const int v = (((int)rintf(nx)) << 10) + (((int)rintf(ny)) << 5) + (int)rintf(nz);
  vid[idx] = v;
  atomicAdd(&hist[(b << 15) + v], 1);
}

// ---------------- per-batch exclusive scan of 32768-bin histogram ----------------
__launch_bounds__(1024)
__global__ void k_scan(const int* __restrict__ hist, int* __restrict__ start,
                       int* __restrict__ cursor) {
  const int b = blockIdx.x, t = threadIdx.x;
  __shared__ int sdata[1024];
  const int base = (b << 15) + t * 32;
  int h[32];
  int sum = 0;
#pragma unroll
  for (int i = 0; i < 32; ++i) {
    h[i] = hist[base + i];
    sum += h[i];
  }
  sdata[t] = sum;
  __syncthreads();
  for (int off = 1; off < 1024; off <<= 1) {
    int v = (t >= off) ? sdata[t - off] : 0;
    __syncthreads();
    sdata[t] += v;
    __syncthreads();
  }
  int run = sdata[t] - sum;  // exclusive prefix of this thread's chunk
#pragma unroll
  for (int i = 0; i < 32; ++i) {
    start[base + i] = run;
    cursor[base + i] = run;
    run += h[i];
  }
}

// ---------------- scatter point indices into sorted order ----------------
__global__ void k_scatteridx(const int* __restrict__ vid, int* __restrict__ cursor,
                             int* __restrict__ order) {
  const int idx = blockIdx.x * 256 + threadIdx.x;  // 262144
  const int b = idx >> 15, n = idx & 32767;
  const int v = vid[idx];
  const int pos = atomicAdd(&cursor[(b << 15) + v], 1);
  order[(b << 15) + pos] = n;
}

// ---------------- features [b][c][n] f32 -> [b][n][c] f32 ----------------
__global__ void k_transpose(const float* __restrict__ feat, float* __restrict__ featT) {
  __shared__ float tile[64][65];
  const int t = threadIdx.x;
  const int b = blockIdx.y;
  const int n0 = blockIdx.x << 6;
#pragma unroll
  for (int i = 0; i < 16; ++i) {
    const int li = i * 256 + t;
    const int c = li >> 6, n = li & 63;
    tile[n][c] = feat[((size_t)(b * 64 + c) << 15) + n0 + n];
  }
  __syncthreads();
#pragma unroll
  for (int i = 0; i < 16; ++i) {
    const int li = i * 256 + t;
    const int n = li >> 6, c = li & 63;
    featT[(((size_t)(b << 15) + n0 + n) << 6) + c] = tile[n][c];
  }
}

// ---------------- gather-reduce per voxel -> bf16 grid [b][v][64] ----------------
__launch_bounds__(256)
__global__ void k_gather(const float* __restrict__ featT, const int* __restrict__ order,
                         const int* __restrict__ start, u16* __restrict__ gb) {
  const int t = threadIdx.x;
  const int b = blockIdx.y;
  const int v = (blockIdx.x << 2) + (t >> 6);
  const int c = t & 63;
  const int s = start[(b << 15) + v];
  const int e = (v == 32767) ? 32768 : start[(b << 15) + v + 1];
  float acc = 0.f;
  for (int p = s; p < e; ++p) {
    const int n = order[(b << 15) + p];
    acc += featT[(((size_t)(b << 15) + n) << 6) + c];
  }
  const float inv = 1.0f / (float)max(e - s, 1);
  gb[(((size_t)(b << 15) + v) << 6) + c] = f2bf(acc * inv);
}

// ---------------- weight repack: [co][ci][27] f32 -> [off][co][ci] bf16 ----------------
template <int CI>
__global__ void k_prepw(const float* __restrict__ w, u16* __restrict__ wr) {
  const int idx = blockIdx.x * 256 + threadIdx.x;
  if (idx >= 27 * 128 * CI) return;
  const int off = idx / (128 * CI);
  const int rem = idx - off * (128 * CI);
  const int co = rem / CI;
  const int ci = rem - co * CI;
  wr[idx] = f2bf(w[(co * CI + ci) * 27 + off]);
}

// ---------------- conv3d 3x3x3 SAME, implicit GEMM via MFMA bf16 ----------------
// in:[8][32768(v=x*1024+y*32+z)][CI] bf16, W:[27][128][CI] bf16, out:[8][32768][128] bf16
// block: (x-quad, y, b); M=128 co x N=128 (4 z-pencils). 4 waves, each 4mx4n 16x16 tiles.
template <int CI>
__launch_bounds__(256, 2)
__global__ void k_conv(const u16* __restrict__ in, const u16* __restrict__ W,
                       const float* __restrict__ bias, u16* __restrict__ outp,
                       float* __restrict__ ssum, float* __restrict__ ssq) {
  constexpr int CIC = 40;  // padded ci stride (keeps ds_read_b128 aligned, spreads banks)
  __shared__ u16 lin[612 * CIC];  // [xs6][ys3][z34][40] = 48960 B
  const int t = threadIdx.x;
  const int wave = t >> 6, lane = t & 63;
  const int l15 = lane & 15, quad = lane >> 4;
  const int x0 = blockIdx.x << 2;
  const int y = blockIdx.y;
  const int b = blockIdx.z;
  const int mq = wave & 1, nq = wave >> 1;

  f32x4 acc[4][4];
#pragma unroll
  for (int i = 0; i < 4; ++i)
#pragma unroll
    for (int j = 0; j < 4; ++j) acc[i][j] = (f32x4)0.0f;

  for (int cc = 0; cc < CI / 32; ++cc) {
    __syncthreads();
    const int ci0 = cc << 5;
    for (int id = t; id < 2448; id += 256) {  // 612 rows x 4 x 16B
      const int row = id >> 2, c16 = id & 3;
      const int xs = row / 102, rem = row - xs * 102;
      const int ys = rem / 34, zp = rem - ys * 34;
      const int x = x0 + xs - 1, yy = y + ys - 1, zz = zp - 1;
      uint4 val = make_uint4(0u, 0u, 0u, 0u);
      if ((u32)x < 32u && (u32)yy < 32u && (u32)zz < 32u)
        val = *(const uint4*)(in + (((b << 15) + (x << 10) + (yy << 5) + zz) * CI + ci0 + (c16 << 3)));
      *(uint4*)(lin + row * CIC + (c16 << 3)) = val;
    }
    __syncthreads();

#pragma unroll 1
    for (int off = 0; off < 27; ++off) {
      const int dx = off / 9, r9 = off - dx * 9;
      const int dy = r9 / 3, dz = r9 - dy * 3;
      bf16x8 af[4];
#pragma unroll
      for (int mt = 0; mt < 4; ++mt) {
        const int co = (mq << 6) + (mt << 4) + l15;
        af[mt] = *(const bf16x8*)(W + ((off << 7) + co) * CI + ci0 + (quad << 3));
      }
      bf16x8 bfr[4];
#pragma unroll
      for (int nt = 0; nt < 4; ++nt) {
        const int px = (nq << 1) + (nt >> 1);
        const int z = ((nt & 1) << 4) + l15;
        const int rowi = ((px + dx) * 3 + dy) * 34 + z + dz;
        bfr[nt] = *(const bf16x8*)(lin + rowi * CIC + (quad << 3));
      }
#pragma unroll
      for (int mt = 0; mt < 4; ++mt)
#pragma unroll
        for (int nt = 0; nt < 4; ++nt)
          acc[mt][nt] = __builtin_amdgcn_mfma_f32_16x16x32_bf16(af[mt], bfr[nt], acc[mt][nt], 0, 0, 0);
    }
  }

  // epilogue: +bias, bf16 store, per-channel sum/sumsq (for GN)
  float ps[16], pq[16];
#pragma unroll
  for (int i = 0; i < 16; ++i) { ps[i] = 0.f; pq[i] = 0.f; }
#pragma unroll
  for (int mt = 0; mt < 4; ++mt) {
    const int co0 = (mq << 6) + (mt << 4) + (quad << 2);
    const float4 b4 = *(const float4*)(bias + co0);
#pragma unroll
    for (int nt = 0; nt < 4; ++nt) {
      const int px = (nq << 1) + (nt >> 1);
      const int z = ((nt & 1) << 4) + l15;
      const int v = ((x0 + px) << 10) + (y << 5) + z;
      const float v0 = acc[mt][nt][0] + b4.x;
      const float v1 = acc[mt][nt][1] + b4.y;
      const float v2 = acc[mt][nt][2] + b4.z;
      const float v3 = acc[mt][nt][3] + b4.w;
      ps[mt * 4 + 0] += v0; pq[mt * 4 + 0] += v0 * v0;
      ps[mt * 4 + 1] += v1; pq[mt * 4 + 1] += v1 * v1;
      ps[mt * 4 + 2] += v2; pq[mt * 4 + 2] += v2 * v2;
      ps[mt * 4 + 3] += v3; pq[mt * 4 + 3] += v3 * v3;
      uint2 pk;
      pk.x = (u32)f2bf(v0) | ((u32)f2bf(v1) << 16);
      pk.y = (u32)f2bf(v2) | ((u32)f2bf(v3) << 16);
      *(uint2*)(outp + ((b << 15) + v) * 128 + co0) = pk;
    }
  }
#pragma unroll
  for (int i = 0; i < 16; ++i) {
#pragma unroll
    for (int d = 1; d < 16; d <<= 1) {
      ps[i] += __shfl_xor(ps[i], d);
      pq[i] += __shfl_xor(pq[i], d);
    }
  }
  if (l15 == 0) {
#pragma unroll
    for (int mt = 0; mt < 4; ++mt)
#pragma unroll
      for (int r = 0; r < 4; ++r) {
        const int co = (mq << 6) + (mt << 4) + (quad << 2) + r;
        atomicAdd(&ssum[b * 128 + co], ps[mt * 4 + r]);
        atomicAdd(&ssq[b * 128 + co], pq[mt * 4 + r]);
      }
  }
}

// ---------------- GN -> per-(b,c) affine ----------------
__global__ void k_gnaff(const float* __restrict__ s, const float* __restrict__ q,
                        const float* __restrict__ gg, const float* __restrict__ gb,
                        float* __restrict__ A, float* __restrict__ B) {
  const int b = blockIdx.x, c = threadIdx.x;  // 128 threads
  __shared__ float gs[8], gq[8];
  if (c < 8) { gs[c] = 0.f; gq[c] = 0.f; }
  __syncthreads();
  const float sc = s[b * 128 + c], qc = q[b * 128 + c];
  atomicAdd(&gs[c >> 4], sc);
  atomicAdd(&gq[c >> 4], qc);
  __syncthreads();
  const float inv = 1.0f / 524288.0f;  // 16 ch * 32768
  const float mg = gs[c >> 4] * inv;
  const float var = gq[c >> 4] * inv - mg * mg;
  const float rs = rsqrtf(var + 1e-5f);
  const float a = gg[c] * rs;
  A[b * 128 + c] = a;
  B[b * 128 + c] = gb[c] - mg * a;
}

// ---------------- GN2 + SE -> per-(b,c) affine ----------------
__global__ void k_se(const float* __restrict__ s, const float* __restrict__ q,
                     const float* __restrict__ gg, const float* __restrict__ gb,
                     const float* __restrict__ w1, const float* __restrict__ b1,
                     const float* __restrict__ w2, const float* __restrict__ b2,
                     float* __restrict__ A, float* __restrict__ B) {
  const int b = blockIdx.x, c = threadIdx.x;  // 128 threads
  __shared__ float gs[8], gq[8], sarr[128], h[16];
  if (c < 8) { gs[c] = 0.f; gq[c] = 0.f; }
  __syncthreads();
  const float sc = s[b * 128 + c], qc = q[b * 128 + c];
  atomicAdd(&gs[c >> 4], sc);
  atomicAdd(&gq[c >> 4], qc);
  __syncthreads();
  const float inv = 1.0f / 524288.0f;
  const float mg = gs[c >> 4] * inv;
  const float var = gq[c >> 4] * inv - mg * mg;
  const float rs = rsqrtf(var + 1e-5f);
  const float a = gg[c] * rs;
  const float bb = gb[c] - mg * a;
  sarr[c] = (sc * (1.0f / 32768.0f)) * a + bb;  // spatial mean of GN output
  __syncthreads();
  if (c < 16) {
    float accv = b1[c];
    for (int i = 0; i < 128; ++i) accv += w1[c * 128 + i] * sarr[i];
    h[c] = fmaxf(accv, 0.f);
  }
  __syncthreads();
  float o = b2[c];
  for (int r = 0; r < 16; ++r) o += w2[c * 16 + r] * h[r];
  const float se = 1.0f / (1.0f + __expf(-o));
  A[b * 128 + c] = a * se;
  B[b * 128 + c] = bb * se;
}

// ---------------- GN1 apply + swish, bf16->bf16 ----------------
__global__ void k_gnapply(const u16* __restrict__ x, const float* __restrict__ A,
                          const float* __restrict__ B, u16* __restrict__ outp) {
  const int idx = blockIdx.x * 256 + threadIdx.x;  // 4194304
  const int e0 = idx << 3;
  const int b = e0 >> 22;
  const int c0 = e0 & 127;
  const uint4 v = ((const uint4*)x)[idx];
  const float* Ab = A + b * 128 + c0;
  const float* Bb = B + b * 128 + c0;
  u32 vv[4] = {v.x, v.y, v.z, v.w};
  uint4 o;
  u32 rr[4];
#pragma unroll
  for (int i = 0; i < 4; ++i) {
    float y0 = bf2f(vv[i] & 0xffffu) * Ab[2 * i] + Bb[2 * i];
    float y1 = bf2f(vv[i] >> 16) * Ab[2 * i + 1] + Bb[2 * i + 1];
    y0 = swishf(y0);
    y1 = swishf(y1);
    rr[i] = (u32)f2bf(y0) | ((u32)f2bf(y1) << 16);
  }
  o.x = rr[0]; o.y = rr[1]; o.z = rr[2]; o.w = rr[3];
  ((uint4*)outp)[idx] = o;
}

// ---------------- point branch GEMM: pt = pt_w @ features + b -> d_out (raw f32) ----------------
__launch_bounds__(256, 2)
__global__ void k_pt(const float* __restrict__ feat, const float* __restrict__ pw,
                     const float* __restrict__ pb, float* __restrict__ outp,
                     float* __restrict__ ssum, float* __restrict__ ssq) {
  __shared__ float fl[64 * 64];    // [k][n]
  __shared__ float wl[64 * 132];   // [k][c] padded
  const int t = threadIdx.x;
  const int n0g = blockIdx.x << 6;
  const int b = blockIdx.y;
  for (int i = t; i < 1024; i += 256) {
    const int fi = i << 2;
    const int k = fi >> 6, n = fi & 63;
    *(float4*)(fl + fi) = *(const float4*)(feat + ((size_t)(b * 64 + k) << 15) + n0g + n);
  }
  for (int i = t; i < 8192; i += 256) {
    const int c = i >> 6, k = i & 63;
    wl[k * 132 + c] = pw[i];
  }
  __syncthreads();
  const int tc = t >> 3, tn = t & 7;
  const int c0 = tc << 2, n0 = tn << 3;
  float acc[4][8];
#pragma unroll
  for (int i = 0; i < 4; ++i)
#pragma unroll
    for (int j = 0; j < 8; ++j) acc[i][j] = 0.f;
#pragma unroll 4
  for (int k = 0; k < 64; ++k) {
    const float4 a4 = *(const float4*)(wl + k * 132 + c0);
    const float4 b0 = *(const float4*)(fl + (k << 6) + n0);
    const float4 b1 = *(const float4*)(fl + (k << 6) + n0 + 4);
    const float av[4] = {a4.x, a4.y, a4.z, a4.w};
    const float bv[8] = {b0.x, b0.y, b0.z, b0.w, b1.x, b1.y, b1.z, b1.w};
#pragma unroll
    for (int i = 0; i < 4; ++i)
#pragma unroll
      for (int j = 0; j < 8; ++j) acc[i][j] += av[i] * bv[j];
  }
#pragma unroll
  for (int i = 0; i < 4; ++i) {
    const int c = c0 + i;
    const float bias = pb[c];
    float s = 0.f, q = 0.f;
    float vv[8];
#pragma unroll
    for (int j = 0; j < 8; ++j) {
      vv[j] = acc[i][j] + bias;
      s += vv[j];
      q += vv[j] * vv[j];
    }
    float4 o0, o1;
    o0.x = vv[0]; o0.y = vv[1]; o0.z = vv[2]; o0.w = vv[3];
    o1.x = vv[4]; o1.y = vv[5]; o1.z = vv[6]; o1.w = vv[7];
    float* op = outp + (((size_t)(b * 128 + c)) << 15) + n0g + n0;
    *(float4*)op = o0;
    *(float4*)(op + 4) = o1;
    for (int d = 1; d < 8; d <<= 1) {
      s += __shfl_xor(s, d);
      q += __shfl_xor(q, d);
    }
    if (tn == 0) {
      atomicAdd(&ssum[b * 128 + c], s);
      atomicAdd(&ssq[b * 128 + c], q);
    }
  }
}

// ---------------- trilinear devox (w/ GN2*SE affine) + point branch (GN3 affine + swish) ----------------
__launch_bounds__(256)
__global__ void k_devox(const u16* __restrict__ g, const float4* __restrict__ nrm,
                        const float* __restrict__ A2, const float* __restrict__ B2,
                        const float* __restrict__ A3, const float* __restrict__ B3,
                        float* __restrict__ outp) {
  __shared__ float tri[64][129];
  const int t = threadIdx.x;
  const int blk = blockIdx.x, b = blockIdx.y;
  {
    const int pl = t & 63, cg = t >> 6;
    const float4 nc = nrm[(b << 15) + blk * 64 + pl];
    const int ix0 = (int)floorf(nc.x), iy0 = (int)floorf(nc.y), iz0 = (int)floorf(nc.z);
    const float rx = nc.x - (float)ix0, ry = nc.y - (float)iy0, rz = nc.z - (float)iz0;
    const int ix1 = min(ix0 + 1, 31), iy1 = min(iy0 + 1, 31), iz1 = min(iz0 + 1, 31);
    float acc[32];
#pragma unroll
    for (int i = 0; i < 32; ++i) acc[i] = 0.f;
    for (int cr = 0; cr < 8; ++cr) {
      const int xx = (cr & 4) ? ix1 : ix0;
      const int yv = (cr & 2) ? iy1 : iy0;
      const int zv = (cr & 1) ? iz1 : iz0;
      const float w = ((cr & 4) ? rx : 1.f - rx) * ((cr & 2) ? ry : 1.f - ry) *
                      ((cr & 1) ? rz : 1.f - rz);
      const uint4* src =
          (const uint4*)(g + ((size_t)((b << 15) + (xx << 10) + (yv << 5) + zv) << 7) + (cg << 5));
#pragma unroll
      for (int qq = 0; qq < 4; ++qq) {
        const uint4 u = src[qq];
        acc[qq * 8 + 0] += w * bf2f(u.x & 0xffffu);
        acc[qq * 8 + 1] += w * bf2f(u.x >> 16);
        acc[qq * 8 + 2] += w * bf2f(u.y & 0xffffu);
        acc[qq * 8 + 3] += w * bf2f(u.y >> 16);
        acc[qq * 8 + 4] += w * bf2f(u.z & 0xffffu);
        acc[qq * 8 + 5] += w * bf2f(u.z >> 16);
        acc[qq * 8 + 6] += w * bf2f(u.w & 0xffffu);
        acc[qq * 8 + 7] += w * bf2f(u.w >> 16);
      }
    }
    const int cb = b * 128 + (cg << 5);
#pragma unroll
    for (int i = 0; i < 32; ++i) tri[pl][(cg << 5) + i] = acc[i] * A2[cb + i] + B2[cb + i];
  }
  __syncthreads();
  {
    const int nl = t & 63, cg = t >> 6;
#pragma unroll 4
    for (int i = 0; i < 32; ++i) {
      const int c = (cg << 5) + i;
      const size_t oi = (((size_t)(b * 128 + c)) << 15) + blk * 64 + nl;
      const float pv = outp[oi];
      const float y = pv * A3[b * 128 + c] + B3[b * 128 + c];
      outp[oi] = tri[nl][c] + swishf(y);
    }
  }
}

extern "C" void kernel_launch(void* const* d_in, const int* in_sizes, int n_in,
                              void* d_out, int out_size, void* d_ws, size_t ws_size,
                              hipStream_t stream) {
  const float* features = (const float*)d_in[0];
  const float* coords = (const float*)d_in[1];
  const float* conv1_w = (const float*)d_in[2];
  const float* conv1_b = (const float*)d_in[3];
  const float* gn1_g = (const float*)d_in[4];
  const float* gn1_b = (const float*)d_in[5];
  const float* conv2_w = (const float*)d_in[6];
  const float* conv2_b = (const float*)d_in[7];
  const float* gn2_g = (const float*)d_in[8];
  const float* gn2_b = (const float*)d_in[9];
  const float* se_w1 = (const float*)d_in[10];
  const float* se_b1 = (const float*)d_in[11];
  const float* se_w2 = (const float*)d_in[12];
  const float* se_b2 = (const float*)d_in[13];
  const float* pt_w = (const float*)d_in[14];
  const float* pt_b = (const float*)d_in[15];
  const float* ptgn_g = (const float*)d_in[16];
  const float* ptgn_b = (const float*)d_in[17];

  char* ws = (char*)d_ws;
  // stats block (zeroed): cstat[32] | s1,q1 | s2,q2 | s3,q3 | A1,B1 | A2,B2 | A3,B3
  float* cstat = (float*)ws;
  float* s1 = cstat + 32;
  float* q1 = s1 + 1024;
  float* s2 = q1 + 1024;
  float* q2 = s2 + 1024;
  float* s3 = q2 + 1024;
  float* q3 = s3 + 1024;
  float* A1 = q3 + 1024;
  float* B1 = A1 + 1024;
  float* A2 = B1 + 1024;
  float* B2 = A2 + 1024;
  float* A3 = B2 + 1024;
  float* B3 = A3 + 1024;
  size_t o = 65536;
  u16* Wr1 = (u16*)(ws + o); o += (size_t)27 * 128 * 64 * 2;
  u16* Wr2 = (u16*)(ws + o); o += (size_t)27 * 128 * 128 * 2;
  o = (o + 255) & ~(size_t)255;
  float4* nrm = (float4*)(ws + o); o += (size_t)8 * 32768 * 16;
  char* regA = ws + o; o += (size_t)8 * 32768 * 128 * 2;  // featT f32 / conv1raw / conv2raw
  u16* gridbf = (u16*)(ws + o); o += (size_t)8 * 32768 * 64 * 2;
  u16* c2in = (u16*)(ws + o); o += (size_t)8 * 32768 * 128 * 2;
  int* vid = (int*)(ws + o); o += (size_t)8 * 32768 * 4;
  int* hist = (int*)(ws + o); o += (size_t)8 * 32768 * 4;
  int* startb = (int*)(ws + o); o += (size_t)8 * 32768 * 4;
  int* cursor = (int*)(ws + o); o += (size_t)8 * 32768 * 4;
  int* order = (int*)(ws + o); o += (size_t)8 * 32768 * 4;
  float* featT = (float*)regA;
  u16* c1raw = (u16*)regA;
  u16* c2raw = (u16*)regA;

  hipMemsetAsync(cstat, 0, 65536, stream);
  hipMemsetAsync(hist, 0, (size_t)8 * 32768 * 4, stream);

  k_prepw<64><<<dim3((27 * 128 * 64 + 255) / 256), 256, 0, stream>>>(conv1_w, Wr1);
  k_prepw<128><<<dim3((27 * 128 * 128 + 255) / 256), 256, 0, stream>>>(conv2_w, Wr2);
  k_csum<<<dim3(32, 8), 256, 0, stream>>>(coords, cstat);
  k_cmax<<<dim3(32, 8), 256, 0, stream>>>(coords, cstat);
  k_count<<<1024, 256, 0, stream>>>(coords, cstat, nrm, vid, hist);
  k_scan<<<8, 1024, 0, stream>>>(hist, startb, cursor);
  k_scatteridx<<<1024, 256, 0, stream>>>(vid, cursor, order);
  k_transpose<<<dim3(512, 8), 256, 0, stream>>>(features, featT);
  k_gather<<<dim3(8192, 8), 256, 0, stream>>>(featT, order, startb, gridbf);
  k_conv<64><<<dim3(8, 32, 8), 256, 0, stream>>>(gridbf, Wr1, conv1_b, c1raw, s1, q1);
  k_gnaff<<<8, 128, 0, stream>>>(s1, q1, gn1_g, gn1_b, A1, B1);
  k_gnapply<<<16384, 256, 0, stream>>>(c1raw, A1, B1, c2in);
  k_conv<128><<<dim3(8, 32, 8), 256, 0, stream>>>(c2in, Wr2, conv2_b, c2raw, s2, q2);
  k_pt<<<dim3(512, 8), 256, 0, stream>>>(features, pt_w, pt_b, (float*)d_out, s3, q3);
  k_se<<<8, 128, 0, stream>>>(s2, q2, gn2_g, gn2_b, se_w1, se_b1, se_w2, se_b2, A2, B2);
  k_gnaff<<<8, 128, 0, stream>>>(s3, q3, ptgn_g, ptgn_b, A3, B3);
  k_devox<<<dim3(512, 8), 256, 0, stream>>>(c2raw, nrm, A2, B2, A3, B3, (float*)d_out);
}

// Round 3
// 1627.487 us; speedup vs baseline: 1.5423x; 1.0747x over previous
//
#include <hip/hip_runtime.h>
#include <cmath>

typedef unsigned short u16;
typedef unsigned int u32;
typedef __bf16 bf16x8 __attribute__((ext_vector_type(8)));
typedef float f32x4 __attribute__((ext_vector_type(4)));

__device__ __forceinline__ u16 f2bf(float f) {
  u32 u = __float_as_uint(f);
  u32 r = (u + 0x7FFFu + ((u >> 16) & 1u)) >> 16;
  return (u16)r;
}
__device__ __forceinline__ float bf2f(u32 h) { return __uint_as_float(h << 16); }
__device__ __forceinline__ float swishf(float y) { return y / (1.0f + __expf(-y)); }

// ---------------- coord sums: atomic per-block partial sums ----------------
// cstat layout per b: [sx, sy, sz, maxnorm_bits]
__global__ void k_csum(const float* __restrict__ coords, float* __restrict__ cstat) {
  const int b = blockIdx.y, t = threadIdx.x;
  const int n0 = blockIdx.x * 1024;
  float s[3] = {0.f, 0.f, 0.f};
#pragma unroll
  for (int a = 0; a < 3; ++a) {
    const float* p = coords + (b * 3 + a) * 32768 + n0;
#pragma unroll
    for (int i = 0; i < 4; ++i) s[a] += p[t + i * 256];
  }
#pragma unroll
  for (int a = 0; a < 3; ++a) {
#pragma unroll
    for (int d = 1; d < 64; d <<= 1) s[a] += __shfl_xor(s[a], d);
    if ((t & 63) == 0) atomicAdd(&cstat[b * 4 + a], s[a]);
  }
}

__global__ void k_cmax(const float* __restrict__ coords, float* __restrict__ cstat) {
  const int b = blockIdx.y, t = threadIdx.x;
  const int n0 = blockIdx.x * 1024;
  const float mx = cstat[b * 4 + 0] * (1.0f / 32768.0f);
  const float my = cstat[b * 4 + 1] * (1.0f / 32768.0f);
  const float mz = cstat[b * 4 + 2] * (1.0f / 32768.0f);
  float mv = 0.f;
#pragma unroll
  for (int i = 0; i < 4; ++i) {
    const int n = n0 + t + i * 256;
    const float dx = coords[(b * 3 + 0) * 32768 + n] - mx;
    const float dy = coords[(b * 3 + 1) * 32768 + n] - my;
    const float dz = coords[(b * 3 + 2) * 32768 + n] - mz;
    mv = fmaxf(mv, dx * dx + dy * dy + dz * dz);
  }
#pragma unroll
  for (int d = 1; d < 64; d <<= 1) mv = fmaxf(mv, __shfl_xor(mv, d));
  if ((t & 63) == 0) atomicMax((u32*)&cstat[b * 4 + 3], __float_as_uint(sqrtf(mv)));
}

// ---------------- normalize coords, voxel id, histogram ----------------
__global__ void k_count(const float* __restrict__ coords, const float* __restrict__ cstat,
                        float4* __restrict__ nrm, int* __restrict__ vid, int* __restrict__ hist) {
  const int idx = blockIdx.x * 256 + threadIdx.x;  // 262144
  const int b = idx >> 15, n = idx & 32767;
  const float mx = cstat[b * 4 + 0] * (1.0f / 32768.0f);
  const float my = cstat[b * 4 + 1] * (1.0f / 32768.0f);
  const float mz = cstat[b * 4 + 2] * (1.0f / 32768.0f);
  const float mn = __uint_as_float(__float_as_uint(cstat[b * 4 + 3]));
  const float inv = 1.0f / (mn * 2.0f);
  float nx = ((coords[(b * 3 + 0) * 32768 + n] - mx) * inv + 0.5f) * 32.0f;
  float ny = ((coords[(b * 3 + 1) * 32768 + n] - my) * inv + 0.5f) * 32.0f;
  float nz = ((coords[(b * 3 + 2) * 32768 + n] - mz) * inv + 0.5f) * 32.0f;
  nx = fminf(fmaxf(nx, 0.0f), 31.0f);
  ny = fminf(fmaxf(ny, 0.0f), 31.0f);
  nz = fminf(fmaxf(nz, 0.0f), 31.0f);
  float4 o; o.x = nx; o.y = ny; o.z = nz; o.w = 0.f;
  nrm[idx] = o;
  const int v = (((int)rintf(nx)) << 10) + (((int)rintf(ny)) << 5) + (int)rintf(nz);
  vid[idx] = v;
  atomicAdd(&hist[(b << 15) + v], 1);
}

// ---------------- per-batch exclusive scan of 32768-bin histogram ----------------
__launch_bounds__(1024)
__global__ void k_scan(const int* __restrict__ hist, int* __restrict__ start,
                       int* __restrict__ cursor) {
  const int b = blockIdx.x, t = threadIdx.x;
  __shared__ int sdata[1024];
  const int base = (b << 15) + t * 32;
  int h[32];
  int sum = 0;
#pragma unroll
  for (int i = 0; i < 32; ++i) {
    h[i] = hist[base + i];
    sum += h[i];
  }
  sdata[t] = sum;
  __syncthreads();
  for (int off = 1; off < 1024; off <<= 1) {
    int v = (t >= off) ? sdata[t - off] : 0;
    __syncthreads();
    sdata[t] += v;
    __syncthreads();
  }
  int run = sdata[t] - sum;  // exclusive prefix of this thread's chunk
#pragma unroll
  for (int i = 0; i < 32; ++i) {
    start[base + i] = run;
    cursor[base + i] = run;
    run += h[i];
  }
}

// ---------------- scatter point indices into sorted order ----------------
__global__ void k_scatteridx(const int* __restrict__ vid, int* __restrict__ cursor,
                             int* __restrict__ order) {
  const int idx = blockIdx.x * 256 + threadIdx.x;  // 262144
  const int b = idx >> 15, n = idx & 32767;
  const int v = vid[idx];
  const int pos = atomicAdd(&cursor[(b << 15) + v], 1);
  order[(b << 15) + pos] = n;
}

// ---------------- features [b][c][n] f32 -> [b][n][c] f32 ----------------
__global__ void k_transpose(const float* __restrict__ feat, float* __restrict__ featT) {
  __shared__ float tile[64][65];
  const int t = threadIdx.x;
  const int b = blockIdx.y;
  const int n0 = blockIdx.x << 6;
#pragma unroll
  for (int i = 0; i < 16; ++i) {
    const int li = i * 256 + t;
    const int c = li >> 6, n = li & 63;
    tile[n][c] = feat[((size_t)(b * 64 + c) << 15) + n0 + n];
  }
  __syncthreads();
#pragma unroll
  for (int i = 0; i < 16; ++i) {
    const int li = i * 256 + t;
    const int n = li >> 6, c = li & 63;
    featT[(((size_t)(b << 15) + n0 + n) << 6) + c] = tile[n][c];
  }
}

// ---------------- gather-reduce per voxel -> bf16 grid [b][v][64] ----------------
__launch_bounds__(256)
__global__ void k_gather(const float* __restrict__ featT, const int* __restrict__ order,
                         const int* __restrict__ start, u16* __restrict__ gb) {
  const int t = threadIdx.x;
  const int b = blockIdx.y;
  const int v = (blockIdx.x << 2) + (t >> 6);
  const int c = t & 63;
  const int s = start[(b << 15) + v];
  const int e = (v == 32767) ? 32768 : start[(b << 15) + v + 1];
  float acc = 0.f;
  for (int p = s; p < e; ++p) {
    const int n = order[(b << 15) + p];
    acc += featT[(((size_t)(b << 15) + n) << 6) + c];
  }
  const float inv = 1.0f / (float)max(e - s, 1);
  gb[(((size_t)(b << 15) + v) << 6) + c] = f2bf(acc * inv);
}

// ---------------- weight repack: [co][ci][27] f32 -> [off][co][ci] bf16 ----------------
template <int CI>
__global__ void k_prepw(const float* __restrict__ w, u16* __restrict__ wr) {
  const int idx = blockIdx.x * 256 + threadIdx.x;
  if (idx >= 27 * 128 * CI) return;
  const int off = idx / (128 * CI);
  const int rem = idx - off * (128 * CI);
  const int co = rem / CI;
  const int ci = rem - co * CI;
  wr[idx] = f2bf(w[(co * CI + ci) * 27 + off]);
}

// ---------------- conv3d 3x3x3 SAME, implicit GEMM via MFMA bf16 ----------------
// in:[8][32768(v=x*1024+y*32+z)][CI] bf16, W:[27][128][CI] bf16, out:[8][32768][128] bf16
// block: (x-quad, y, b); M=128 co x N=128 (4 z-pencils). 4 waves, each 4mx4n 16x16 tiles.
// FUSE: apply per-input-channel affine (A,B) + swish during LDS staging (in-bounds only;
//       halo stays 0, matching SAME zero-padding of the activated tensor).
// Off-loop is software-pipelined 2-deep: loads for offset k+1 overlap MFMAs of offset k.
template <int CI, bool FUSE>
__launch_bounds__(256, 2)
__global__ void k_conv(const u16* __restrict__ in, const u16* __restrict__ W,
                       const float* __restrict__ bias,
                       const float* __restrict__ Apre, const float* __restrict__ Bpre,
                       u16* __restrict__ outp, float* __restrict__ ssum,
                       float* __restrict__ ssq) {
  constexpr int CIC = 40;  // padded ci stride (16B-aligned rows; measured conflicts ~4%)
  __shared__ u16 lin[612 * CIC];  // [xs6][ys3][z34][40] = 48960 B
  const int t = threadIdx.x;
  const int wave = t >> 6, lane = t & 63;
  const int l15 = lane & 15, quad = lane >> 4;
  const int x0 = blockIdx.x << 2;
  const int y = blockIdx.y;
  const int b = blockIdx.z;
  const int mq = wave & 1, nq = wave >> 1;

  f32x4 acc[4][4];
#pragma unroll
  for (int i = 0; i < 4; ++i)
#pragma unroll
    for (int j = 0; j < 4; ++j) acc[i][j] = (f32x4)0.0f;

  // LDS fragment-read bases per nt (element index), sans K-offset
  int badr[4];
#pragma unroll
  for (int nt = 0; nt < 4; ++nt) {
    const int px = (nq << 1) + (nt >> 1);
    const int z = ((nt & 1) << 4) + l15;
    badr[nt] = (px * 3 * 34 + z) * CIC + (quad << 3);
  }

  for (int cc = 0; cc < CI / 32; ++cc) {
    const int ci0 = cc << 5;
    float aV[8], bV[8];
    if (FUSE) {
      const int chb = b * 128 + ci0 + (t & 3) * 8;
#pragma unroll
      for (int j = 0; j < 8; ++j) {
        aV[j] = Apre[chb + j];
        bV[j] = Bpre[chb + j];
      }
    }
    __syncthreads();
    for (int id = t; id < 2448; id += 256) {  // 612 rows x 4 x 16B
      const int row = id >> 2, c16 = id & 3;
      const int xs = row / 102, rem = row - xs * 102;
      const int ys = rem / 34, zp = rem - ys * 34;
      const int x = x0 + xs - 1, yy = y + ys - 1, zz = zp - 1;
      uint4 val = make_uint4(0u, 0u, 0u, 0u);
      if ((u32)x < 32u && (u32)yy < 32u && (u32)zz < 32u) {
        val = *(const uint4*)(in + (((b << 15) + (x << 10) + (yy << 5) + zz) * CI + ci0 + (c16 << 3)));
        if (FUSE) {
          u32 w4[4] = {val.x, val.y, val.z, val.w};
#pragma unroll
          for (int j = 0; j < 4; ++j) {
            float y0 = bf2f(w4[j] & 0xffffu) * aV[2 * j] + bV[2 * j];
            float y1 = bf2f(w4[j] >> 16) * aV[2 * j + 1] + bV[2 * j + 1];
            y0 = swishf(y0);
            y1 = swishf(y1);
            w4[j] = (u32)f2bf(y0) | ((u32)f2bf(y1) << 16);
          }
          val.x = w4[0]; val.y = w4[1]; val.z = w4[2]; val.w = w4[3];
        }
      }
      *(uint4*)(lin + row * CIC + (c16 << 3)) = val;
    }
    __syncthreads();

    const u16* wA = W + ((mq << 6) + l15) * CI + ci0 + (quad << 3);

    bf16x8 afA[4], bfA[4], afB[4], bfB[4];

#define LOADF(OFF, AF, BF)                                                  \
  {                                                                         \
    const int _o = (OFF);                                                   \
    const int _dx = _o / 9, _rr = _o - _dx * 9;                             \
    const int _dy = _rr / 3, _dz = _rr - _dy * 3;                           \
    const int _ro = (_dx * 102 + _dy * 34 + _dz) * CIC;                     \
    const u16* _wp = wA + (size_t)_o * (128 * CI);                          \
    AF[0] = *(const bf16x8*)(_wp);                                          \
    AF[1] = *(const bf16x8*)(_wp + 16 * CI);                                \
    AF[2] = *(const bf16x8*)(_wp + 32 * CI);                                \
    AF[3] = *(const bf16x8*)(_wp + 48 * CI);                                \
    BF[0] = *(const bf16x8*)(lin + badr[0] + _ro);                          \
    BF[1] = *(const bf16x8*)(lin + badr[1] + _ro);                          \
    BF[2] = *(const bf16x8*)(lin + badr[2] + _ro);                          \
    BF[3] = *(const bf16x8*)(lin + badr[3] + _ro);                          \
  }

#define MFMAS(AF, BF)                                                       \
  {                                                                         \
    _Pragma("unroll") for (int mt = 0; mt < 4; ++mt)                        \
        _Pragma("unroll") for (int nt = 0; nt < 4; ++nt) acc[mt][nt] =      \
            __builtin_amdgcn_mfma_f32_16x16x32_bf16(AF[mt], BF[nt],         \
                                                    acc[mt][nt], 0, 0, 0);  \
  }

    LOADF(0, afA, bfA);
#pragma unroll 1
    for (int op = 0; op < 13; ++op) {
      const int o2 = op << 1;
      LOADF(o2 + 1, afB, bfB);
      MFMAS(afA, bfA);
      LOADF(o2 + 2, afA, bfA);
      MFMAS(afB, bfB);
    }
    MFMAS(afA, bfA);  // off 26
#undef LOADF
#undef MFMAS
  }

  // epilogue: +bias, bf16 store, per-channel sum/sumsq (for GN)
  float ps[16], pq[16];
#pragma unroll
  for (int i = 0; i < 16; ++i) { ps[i] = 0.f; pq[i] = 0.f; }
#pragma unroll
  for (int mt = 0; mt < 4; ++mt) {
    const int co0 = (mq << 6) + (mt << 4) + (quad << 2);
    const float4 b4 = *(const float4*)(bias + co0);
#pragma unroll
    for (int nt = 0; nt < 4; ++nt) {
      const int px = (nq << 1) + (nt >> 1);
      const int z = ((nt & 1) << 4) + l15;
      const int v = ((x0 + px) << 10) + (y << 5) + z;
      const float v0 = acc[mt][nt][0] + b4.x;
      const float v1 = acc[mt][nt][1] + b4.y;
      const float v2 = acc[mt][nt][2] + b4.z;
      const float v3 = acc[mt][nt][3] + b4.w;
      ps[mt * 4 + 0] += v0; pq[mt * 4 + 0] += v0 * v0;
      ps[mt * 4 + 1] += v1; pq[mt * 4 + 1] += v1 * v1;
      ps[mt * 4 + 2] += v2; pq[mt * 4 + 2] += v2 * v2;
      ps[mt * 4 + 3] += v3; pq[mt * 4 + 3] += v3 * v3;
      uint2 pk;
      pk.x = (u32)f2bf(v0) | ((u32)f2bf(v1) << 16);
      pk.y = (u32)f2bf(v2) | ((u32)f2bf(v3) << 16);
      *(uint2*)(outp + ((b << 15) + v) * 128 + co0) = pk;
    }
  }
#pragma unroll
  for (int i = 0; i < 16; ++i) {
#pragma unroll
    for (int d = 1; d < 16; d <<= 1) {
      ps[i] += __shfl_xor(ps[i], d);
      pq[i] += __shfl_xor(pq[i], d);
    }
  }
  if (l15 == 0) {
#pragma unroll
    for (int mt = 0; mt < 4; ++mt)
#pragma unroll
      for (int r = 0; r < 4; ++r) {
        const int co = (mq << 6) + (mt << 4) + (quad << 2) + r;
        atomicAdd(&ssum[b * 128 + co], ps[mt * 4 + r]);
        atomicAdd(&ssq[b * 128 + co], pq[mt * 4 + r]);
      }
  }
}

// ---------------- GN -> per-(b,c) affine ----------------
__global__ void k_gnaff(const float* __restrict__ s, const float* __restrict__ q,
                        const float* __restrict__ gg, const float* __restrict__ gb,
                        float* __restrict__ A, float* __restrict__ B) {
  const int b = blockIdx.x, c = threadIdx.x;  // 128 threads
  __shared__ float gs[8], gq[8];
  if (c < 8) { gs[c] = 0.f; gq[c] = 0.f; }
  __syncthreads();
  const float sc = s[b * 128 + c], qc = q[b * 128 + c];
  atomicAdd(&gs[c >> 4], sc);
  atomicAdd(&gq[c >> 4], qc);
  __syncthreads();
  const float inv = 1.0f / 524288.0f;  // 16 ch * 32768
  const float mg = gs[c >> 4] * inv;
  const float var = gq[c >> 4] * inv - mg * mg;
  const float rs = rsqrtf(var + 1e-5f);
  const float a = gg[c] * rs;
  A[b * 128 + c] = a;
  B[b * 128 + c] = gb[c] - mg * a;
}

// ---------------- GN2 + SE -> per-(b,c) affine ----------------
__global__ void k_se(const float* __restrict__ s, const float* __restrict__ q,
                     const float* __restrict__ gg, const float* __restrict__ gb,
                     const float* __restrict__ w1, const float* __restrict__ b1,
                     const float* __restrict__ w2, const float* __restrict__ b2,
                     float* __restrict__ A, float* __restrict__ B) {
  const int b = blockIdx.x, c = threadIdx.x;  // 128 threads
  __shared__ float gs[8], gq[8], sarr[128], h[16];
  if (c < 8) { gs[c] = 0.f; gq[c] = 0.f; }
  __syncthreads();
  const float sc = s[b * 128 + c], qc = q[b * 128 + c];
  atomicAdd(&gs[c >> 4], sc);
  atomicAdd(&gq[c >> 4], qc);
  __syncthreads();
  const float inv = 1.0f / 524288.0f;
  const float mg = gs[c >> 4] * inv;
  const float var = gq[c >> 4] * inv - mg * mg;
  const float rs = rsqrtf(var + 1e-5f);
  const float a = gg[c] * rs;
  const float bb = gb[c] - mg * a;
  sarr[c] = (sc * (1.0f / 32768.0f)) * a + bb;  // spatial mean of GN output
  __syncthreads();
  if (c < 16) {
    float accv = b1[c];
    for (int i = 0; i < 128; ++i) accv += w1[c * 128 + i] * sarr[i];
    h[c] = fmaxf(accv, 0.f);
  }
  __syncthreads();
  float o = b2[c];
  for (int r = 0; r < 16; ++r) o += w2[c * 16 + r] * h[r];
  const float se = 1.0f / (1.0f + __expf(-o));
  A[b * 128 + c] = a * se;
  B[b * 128 + c] = bb * se;
}

// ---------------- point branch GEMM: pt = pt_w @ features + b -> d_out (raw f32) ----------------
__launch_bounds__(256, 2)
__global__ void k_pt(const float* __restrict__ feat, const float* __restrict__ pw,
                     const float* __restrict__ pb, float* __restrict__ outp,
                     float* __restrict__ ssum, float* __restrict__ ssq) {
  __shared__ float fl[64 * 64];    // [k][n]
  __shared__ float wl[64 * 132];   // [k][c] padded
  const int t = threadIdx.x;
  const int n0g = blockIdx.x << 6;
  const int b = blockIdx.y;
  for (int i = t; i < 1024; i += 256) {
    const int fi = i << 2;
    const int k = fi >> 6, n = fi & 63;
    *(float4*)(fl + fi) = *(const float4*)(feat + ((size_t)(b * 64 + k) << 15) + n0g + n);
  }
  for (int i = t; i < 8192; i += 256) {
    const int c = i >> 6, k = i & 63;
    wl[k * 132 + c] = pw[i];
  }
  __syncthreads();
  const int tc = t >> 3, tn = t & 7;
  const int c0 = tc << 2, n0 = tn << 3;
  float acc[4][8];
#pragma unroll
  for (int i = 0; i < 4; ++i)
#pragma unroll
    for (int j = 0; j < 8; ++j) acc[i][j] = 0.f;
#pragma unroll 4
  for (int k = 0; k < 64; ++k) {
    const float4 a4 = *(const float4*)(wl + k * 132 + c0);
    const float4 b0 = *(const float4*)(fl + (k << 6) + n0);
    const float4 b1 = *(const float4*)(fl + (k << 6) + n0 + 4);
    const float av[4] = {a4.x, a4.y, a4.z, a4.w};
    const float bv[8] = {b0.x, b0.y, b0.z, b0.w, b1.x, b1.y, b1.z, b1.w};
#pragma unroll
    for (int i = 0; i < 4; ++i)
#pragma unroll
      for (int j = 0; j < 8; ++j) acc[i][j] += av[i] * bv[j];
  }
#pragma unroll
  for (int i = 0; i < 4; ++i) {
    const int c = c0 + i;
    const float bias = pb[c];
    float s = 0.f, q = 0.f;
    float vv[8];
#pragma unroll
    for (int j = 0; j < 8; ++j) {
      vv[j] = acc[i][j] + bias;
      s += vv[j];
      q += vv[j] * vv[j];
    }
    float4 o0, o1;
    o0.x = vv[0]; o0.y = vv[1]; o0.z = vv[2]; o0.w = vv[3];
    o1.x = vv[4]; o1.y = vv[5]; o1.z = vv[6]; o1.w = vv[7];
    float* op = outp + (((size_t)(b * 128 + c)) << 15) + n0g + n0;
    *(float4*)op = o0;
    *(float4*)(op + 4) = o1;
    for (int d = 1; d < 8; d <<= 1) {
      s += __shfl_xor(s, d);
      q += __shfl_xor(q, d);
    }
    if (tn == 0) {
      atomicAdd(&ssum[b * 128 + c], s);
      atomicAdd(&ssq[b * 128 + c], q);
    }
  }
}

// ---------------- trilinear devox (w/ GN2*SE affine) + point branch (GN3 affine + swish) ----------------
__launch_bounds__(256)
__global__ void k_devox(const u16* __restrict__ g, const float4* __restrict__ nrm,
                        const float* __restrict__ A2, const float* __restrict__ B2,
                        const float* __restrict__ A3, const float* __restrict__ B3,
                        float* __restrict__ outp) {
  __shared__ float tri[64][129];
  const int t = threadIdx.x;
  const int blk = blockIdx.x, b = blockIdx.y;
  {
    const int pl = t & 63, cg = t >> 6;
    const float4 nc = nrm[(b << 15) + blk * 64 + pl];
    const int ix0 = (int)floorf(nc.x), iy0 = (int)floorf(nc.y), iz0 = (int)floorf(nc.z);
    const float rx = nc.x - (float)ix0, ry = nc.y - (float)iy0, rz = nc.z - (float)iz0;
    const int ix1 = min(ix0 + 1, 31), iy1 = min(iy0 + 1, 31), iz1 = min(iz0 + 1, 31);
    float acc[32];
#pragma unroll
    for (int i = 0; i < 32; ++i) acc[i] = 0.f;
    for (int cr = 0; cr < 8; ++cr) {
      const int xx = (cr & 4) ? ix1 : ix0;
      const int yv = (cr & 2) ? iy1 : iy0;
      const int zv = (cr & 1) ? iz1 : iz0;
      const float w = ((cr & 4) ? rx : 1.f - rx) * ((cr & 2) ? ry : 1.f - ry) *
                      ((cr & 1) ? rz : 1.f - rz);
      const uint4* src =
          (const uint4*)(g + ((size_t)((b << 15) + (xx << 10) + (yv << 5) + zv) << 7) + (cg << 5));
#pragma unroll
      for (int qq = 0; qq < 4; ++qq) {
        const uint4 u = src[qq];
        acc[qq * 8 + 0] += w * bf2f(u.x & 0xffffu);
        acc[qq * 8 + 1] += w * bf2f(u.x >> 16);
        acc[qq * 8 + 2] += w * bf2f(u.y & 0xffffu);
        acc[qq * 8 + 3] += w * bf2f(u.y >> 16);
        acc[qq * 8 + 4] += w * bf2f(u.z & 0xffffu);
        acc[qq * 8 + 5] += w * bf2f(u.z >> 16);
        acc[qq * 8 + 6] += w * bf2f(u.w & 0xffffu);
        acc[qq * 8 + 7] += w * bf2f(u.w >> 16);
      }
    }
    const int cb = b * 128 + (cg << 5);
#pragma unroll
    for (int i = 0; i < 32; ++i) tri[pl][(cg << 5) + i] = acc[i] * A2[cb + i] + B2[cb + i];
  }
  __syncthreads();
  {
    const int nl = t & 63, cg = t >> 6;
#pragma unroll 4
    for (int i = 0; i < 32; ++i) {
      const int c = (cg << 5) + i;
      const size_t oi = (((size_t)(b * 128 + c)) << 15) + blk * 64 + nl;
      const float pv = outp[oi];
      const float y = pv * A3[b * 128 + c] + B3[b * 128 + c];
      outp[oi] = tri[nl][c] + swishf(y);
    }
  }
}

extern "C" void kernel_launch(void* const* d_in, const int* in_sizes, int n_in,
                              void* d_out, int out_size, void* d_ws, size_t ws_size,
                              hipStream_t stream) {
  const float* features = (const float*)d_in[0];
  const float* coords = (const float*)d_in[1];
  const float* conv1_w = (const float*)d_in[2];
  const float* conv1_b = (const float*)d_in[3];
  const float* gn1_g = (const float*)d_in[4];
  const float* gn1_b = (const float*)d_in[5];
  const float* conv2_w = (const float*)d_in[6];
  const float* conv2_b = (const float*)d_in[7];
  const float* gn2_g = (const float*)d_in[8];
  const float* gn2_b = (const float*)d_in[9];
  const float* se_w1 = (const float*)d_in[10];
  const float* se_b1 = (const float*)d_in[11];
  const float* se_w2 = (const float*)d_in[12];
  const float* se_b2 = (const float*)d_in[13];
  const float* pt_w = (const float*)d_in[14];
  const float* pt_b = (const float*)d_in[15];
  const float* ptgn_g = (const float*)d_in[16];
  const float* ptgn_b = (const float*)d_in[17];

  char* ws = (char*)d_ws;
  // stats block (zeroed): cstat[32] | s1,q1 | s2,q2 | s3,q3 | A1,B1 | A2,B2 | A3,B3
  float* cstat = (float*)ws;
  float* s1 = cstat + 32;
  float* q1 = s1 + 1024;
  float* s2 = q1 + 1024;
  float* q2 = s2 + 1024;
  float* s3 = q2 + 1024;
  float* q3 = s3 + 1024;
  float* A1 = q3 + 1024;
  float* B1 = A1 + 1024;
  float* A2 = B1 + 1024;
  float* B2 = A2 + 1024;
  float* A3 = B2 + 1024;
  float* B3 = A3 + 1024;
  size_t o = 65536;
  u16* Wr1 = (u16*)(ws + o); o += (size_t)27 * 128 * 64 * 2;
  u16* Wr2 = (u16*)(ws + o); o += (size_t)27 * 128 * 128 * 2;
  o = (o + 255) & ~(size_t)255;
  float4* nrm = (float4*)(ws + o); o += (size_t)8 * 32768 * 16;
  char* regA = ws + o; o += (size_t)8 * 32768 * 128 * 2;  // featT f32 / conv1raw / conv2raw
  u16* gridbf = (u16*)(ws + o); o += (size_t)8 * 32768 * 64 * 2;
  u16* c1raw = (u16*)(ws + o); o += (size_t)8 * 32768 * 128 * 2;
  int* vid = (int*)(ws + o); o += (size_t)8 * 32768 * 4;
  int* hist = (int*)(ws + o); o += (size_t)8 * 32768 * 4;
  int* startb = (int*)(ws + o); o += (size_t)8 * 32768 * 4;
  int* cursor = (int*)(ws + o); o += (size_t)8 * 32768 * 4;
  int* order = (int*)(ws + o); o += (size_t)8 * 32768 * 4;
  float* featT = (float*)regA;
  u16* c2raw = (u16*)regA;  // featT dead after k_gather; reuse for conv2 output

  hipMemsetAsync(cstat, 0, 65536, stream);
  hipMemsetAsync(hist, 0, (size_t)8 * 32768 * 4, stream);

  k_prepw<64><<<dim3((27 * 128 * 64 + 255) / 256), 256, 0, stream>>>(conv1_w, Wr1);
  k_prepw<128><<<dim3((27 * 128 * 128 + 255) / 256), 256, 0, stream>>>(conv2_w, Wr2);
  k_csum<<<dim3(32, 8), 256, 0, stream>>>(coords, cstat);
  k_cmax<<<dim3(32, 8), 256, 0, stream>>>(coords, cstat);
  k_count<<<1024, 256, 0, stream>>>(coords, cstat, nrm, vid, hist);
  k_scan<<<8, 1024, 0, stream>>>(hist, startb, cursor);
  k_scatteridx<<<1024, 256, 0, stream>>>(vid, cursor, order);
  k_transpose<<<dim3(512, 8), 256, 0, stream>>>(features, featT);
  k_gather<<<dim3(8192, 8), 256, 0, stream>>>(featT, order, startb, gridbf);
  k_conv<64, false><<<dim3(8, 32, 8), 256, 0, stream>>>(gridbf, Wr1, conv1_b, nullptr, nullptr,
                                                        c1raw, s1, q1);
  k_gnaff<<<8, 128, 0, stream>>>(s1, q1, gn1_g, gn1_b, A1, B1);
  k_conv<128, true><<<dim3(8, 32, 8), 256, 0, stream>>>(c1raw, Wr2, conv2_b, A1, B1,
                                                        c2raw, s2, q2);
  k_pt<<<dim3(512, 8), 256, 0, stream>>>(features, pt_w, pt_b, (float*)d_out, s3, q3);
  k_se<<<8, 128, 0, stream>>>(s2, q2, gn2_g, gn2_b, se_w1, se_b1, se_w2, se_b2, A2, B2);
  k_gnaff<<<8, 128, 0, stream>>>(s3, q3, ptgn_g, ptgn_b, A3, B3);
  k_devox<<<dim3(512, 8), 256, 0, stream>>>(c2raw, nrm, A2, B2, A3, B3, (float*)d_out);
}